// Round 4
// baseline (114.967 us; speedup 1.0000x reference)
//
#include <hip/hip_runtime.h>

// Viterbi trellis quantizer: S=1024 states, K=2 (4 predecessors), CHUNK=4,
// block_size=16 -> T=64 steps/chain, B=4096 chains (16x16 blocks of 1024^2).
//
// beta-formulation: beta[s] = -(alpha[s]-||x||^2)/2,
//   beta_new[s] = M[s>>2] + (cb[s]·x + h[s]),  h = -||cb||^2/2,
// grouped max M[p] = max_j beta[p + 256 j], 2-bit backpointers per group.
//
// R6. Evidence recap:
//  - R5 == R4 (67us, VALU 66.5%) with pin deleted -> pk_fma itself was the
//    regression (VOP3P likely can't source the AGPR-banked codebook).
//  - VALUBusy is a CU-level OR over 4 SIMDs: R3 92% -> per-SIMD issue ~46%,
//    which matches hand-counted ~144 instr/step x 2cyc x 4 waves. So R3 is
//    LATENCY-bound (serial M write->read LDS round trip per step), not
//    issue-bound.
// R6 = R3 scalar-fma structure + TWO independent chains per wave:
//  - in-wave ILP: when chain A stalls on its M round trip, chain B's ~140
//    independent instructions keep the SIMD issuing (guaranteed, unlike
//    wave-scheduler luck with 4 lockstep waves).
//  - codebook registers shared by both chains (zero duplicate cost).
//  - 64-thread blocks, grid 2048 -> 8 blocks/CU = 2 waves/SIMD (grid max).
//    waves_per_eu(2,2): honest 256-reg budget (80 acc + ~110 arch, no spill).
//  - traceback: lane 0 traces chain A, lane 1 chain B, concurrently.
// Tripwire: WRITE_SIZE > 5120 KB = scratch spill -> back off.

#define COLS      1024
#define T_STEPS   64
#define REC_SIZE  (1024 * 1024)

__global__ __launch_bounds__(64)
__attribute__((amdgpu_waves_per_eu(2, 2)))
void viterbi_q(
    const float* __restrict__ arr,
    const float* __restrict__ cbook,
    float* __restrict__ out)
{
    const int lane = threadIdx.x & 63;        // single wave per block
    const int cA   = blockIdx.x << 1;         // chain A (even)
    const int cB   = cA | 1;                  // chain B (odd, same block-row)
    const int rbA  = cA >> 6, cbA = cA & 63;
    const int rbB  = cB >> 6, cbB = cB & 63;

    __shared__ __align__(16) float tile[2][256];   // x chunks, per chain
    __shared__ __align__(16) float Mst[2][256];    // grouped-max M[p], per chain
    __shared__ unsigned char Jb[2][63 * 64];       // packed backpointers
    __shared__ int st_lds[2][64];                  // traced-back states

    // ---- stage both 16x16 tiles into LDS (tile[ch][e], e = r*16 + c) ----
    {
        const int r  = lane >> 2;
        const int c4 = (lane & 3) << 2;
        float4 vA = *(const float4*)(arr + (rbA * 16 + r) * COLS + cbA * 16 + c4);
        float4 vB = *(const float4*)(arr + (rbB * 16 + r) * COLS + cbB * 16 + c4);
        *(float4*)&tile[0][lane << 2] = vA;
        *(float4*)&tile[1][lane << 2] = vB;
    }
    // M starts at 0: iteration t=0 then computes beta0 = cb·x0 + h exactly.
    *(float4*)&Mst[0][lane << 2] = make_float4(0.f, 0.f, 0.f, 0.f);
    *(float4*)&Mst[1][lane << 2] = make_float4(0.f, 0.f, 0.f, 0.f);

    // ---- codebook rows for this lane's 16 states: s = 4*lane + c + 256*j ----
    // SHARED by both chains -> no duplicate register cost.
    float4 a[16];   // raw codebook row
    float  h[16];   // -||row||^2 / 2
    #pragma unroll
    for (int j = 0; j < 4; ++j) {
        #pragma unroll
        for (int c = 0; c < 4; ++c) {
            const int row = (lane << 2) + c + (j << 8);
            float4 v = *(const float4*)(cbook + row * 4);
            a[j * 4 + c] = v;
            h[j * 4 + c] = -0.5f * (v.x * v.x + v.y * v.y +
                                    v.z * v.z + v.w * v.w);
        }
    }

    const float* __restrict__ tA = &tile[0][0];
    const float* __restrict__ tB = &tile[1][0];
    float* __restrict__ MA       = &Mst[0][0];
    float* __restrict__ MB       = &Mst[1][0];
    unsigned char* __restrict__ JA = &Jb[0][0];
    unsigned char* __restrict__ JB = &Jb[1][0];

    // ---- forward recursion, t = 0..62: two independent chains per wave ----
    #pragma unroll 1
    for (int t = 0; t < T_STEPS - 1; ++t) {
        // issue all DS reads up front so their latencies overlap
        const float4 xtA = *(const float4*)&tA[t << 2];
        const float4 xtB = *(const float4*)&tB[t << 2];
        float mjA[4], mjB[4];
        #pragma unroll
        for (int j = 0; j < 4; ++j) mjA[j] = MA[lane + 64 * j];
        #pragma unroll
        for (int j = 0; j < 4; ++j) mjB[j] = MB[lane + 64 * j];

        // ---- chain A ----
        float nmA[4];
        unsigned bpA = 0;
        #pragma unroll
        for (int c = 0; c < 4; ++c) {
            float cand[4];
            #pragma unroll
            for (int j = 0; j < 4; ++j) {
                const float4 av = a[j * 4 + c];
                float acc = fmaf(av.x, xtA.x, h[j * 4 + c]);
                acc = fmaf(av.y, xtA.y, acc);
                acc = fmaf(av.z, xtA.z, acc);
                acc = fmaf(av.w, xtA.w, acc);
                cand[j] = acc + mjA[j];
            }
            const float v = fmaxf(fmaxf(fmaxf(cand[0], cand[1]), cand[2]),
                                  cand[3]);
            // first-max index == reference's first-min over alpha candidates
            const int j = (cand[0] == v) ? 0
                        : (cand[1] == v) ? 1
                        : (cand[2] == v) ? 2 : 3;
            nmA[c] = v;
            bpA |= (unsigned)j << (2 * c);
        }

        // ---- chain B (fully independent -> fills A's stall holes) ----
        float nmB[4];
        unsigned bpB = 0;
        #pragma unroll
        for (int c = 0; c < 4; ++c) {
            float cand[4];
            #pragma unroll
            for (int j = 0; j < 4; ++j) {
                const float4 av = a[j * 4 + c];
                float acc = fmaf(av.x, xtB.x, h[j * 4 + c]);
                acc = fmaf(av.y, xtB.y, acc);
                acc = fmaf(av.z, xtB.z, acc);
                acc = fmaf(av.w, xtB.w, acc);
                cand[j] = acc + mjB[j];
            }
            const float v = fmaxf(fmaxf(fmaxf(cand[0], cand[1]), cand[2]),
                                  cand[3]);
            const int j = (cand[0] == v) ? 0
                        : (cand[1] == v) ? 1
                        : (cand[2] == v) ? 2 : 3;
            nmB[c] = v;
            bpB |= (unsigned)j << (2 * c);
        }

        // wave-lockstep: all lanes issued their M reads above before writes;
        // same-wave DS ops complete in program order.
        *(float4*)&MA[lane << 2] = make_float4(nmA[0], nmA[1], nmA[2], nmA[3]);
        *(float4*)&MB[lane << 2] = make_float4(nmB[0], nmB[1], nmB[2], nmB[3]);
        JA[t * 64 + lane] = (unsigned char)bpA;
        JB[t * 64 + lane] = (unsigned char)bpB;
    }

    // ---- final step t = 63: full argmax over beta_63[0..1023], per chain ----
    int bestsA, bestsB;
    {
        const int t = T_STEPS - 1;
        const float4 xtA = *(const float4*)&tA[t << 2];
        const float4 xtB = *(const float4*)&tB[t << 2];
        float mjA[4], mjB[4];
        #pragma unroll
        for (int j = 0; j < 4; ++j) mjA[j] = MA[lane + 64 * j];
        #pragma unroll
        for (int j = 0; j < 4; ++j) mjB[j] = MB[lane + 64 * j];

        float bvA = -3.4e38f, bvB = -3.4e38f;
        int   bsA = 0,        bsB = 0;
        #pragma unroll
        for (int j = 0; j < 4; ++j) {      // s ascends with (j, c): first-max ok
            #pragma unroll
            for (int c = 0; c < 4; ++c) {
                const float4 av = a[j * 4 + c];
                float accA = fmaf(av.x, xtA.x, h[j * 4 + c]);
                accA = fmaf(av.y, xtA.y, accA);
                accA = fmaf(av.z, xtA.z, accA);
                accA = fmaf(av.w, xtA.w, accA);
                accA += mjA[j];
                if (accA > bvA) { bvA = accA; bsA = (lane << 2) + c + (j << 8); }

                float accB = fmaf(av.x, xtB.x, h[j * 4 + c]);
                accB = fmaf(av.y, xtB.y, accB);
                accB = fmaf(av.z, xtB.z, accB);
                accB = fmaf(av.w, xtB.w, accB);
                accB += mjB[j];
                if (accB > bvB) { bvB = accB; bsB = (lane << 2) + c + (j << 8); }
            }
        }
        // lexicographic (value desc, state asc) butterfly; both chains
        // interleaved so shuffle latencies overlap
        #pragma unroll
        for (int off = 32; off > 0; off >>= 1) {
            const float ovA = __shfl_xor(bvA, off, 64);
            const int   osA = __shfl_xor(bsA, off, 64);
            const float ovB = __shfl_xor(bvB, off, 64);
            const int   osB = __shfl_xor(bsB, off, 64);
            if (ovA > bvA || (ovA == bvA && osA < bsA)) { bvA = ovA; bsA = osA; }
            if (ovB > bvB || (ovB == bvB && osB < bsB)) { bvB = ovB; bsB = osB; }
        }
        bestsA = bsA;
        bestsB = bsB;
    }

    // ---- traceback: lane 0 traces chain A, lane 1 traces chain B ----
    if (lane < 2) {
        const unsigned char* __restrict__ Jp = (lane == 0) ? JA : JB;
        int s = (lane == 0) ? bestsA : bestsB;
        st_lds[lane][T_STEPS - 1] = s;
        for (int i = T_STEPS - 2; i >= 0; --i) {
            const int p = s >> 2;
            const unsigned byte = Jp[i * 64 + (p >> 2)];
            const int j = (byte >> (2 * (p & 3))) & 3;
            s = p + (j << 8);
            st_lds[lane][i] = s;
        }
    }
    // NO barrier: st_lds written by lanes of THIS wave, read by the same wave
    // below; wave-lockstep + in-order same-wave DS makes it visible.

    // ---- outputs: lane i handles step t = i for both chains ----
    const int stA = st_lds[0][lane];
    const int stB = st_lds[1][lane];
    // states_out flat: REC_SIZE + chain*64 + t   (stored as float values)
    out[REC_SIZE + cA * 64 + lane] = (float)stA;
    out[REC_SIZE + cB * 64 + lane] = (float)stB;
    // rec: step t covers elements e = 4t..4t+3 -> row t>>2, cols 4*(t&3)..+3
    const float4 vA = *(const float4*)(cbook + stA * 4);
    const float4 vB = *(const float4*)(cbook + stB * 4);
    const int r  = lane >> 2;
    const int c4 = (lane & 3) << 2;
    *(float4*)(out + (rbA * 16 + r) * COLS + cbA * 16 + c4) = vA;
    *(float4*)(out + (rbB * 16 + r) * COLS + cbB * 16 + c4) = vB;
}

extern "C" void kernel_launch(void* const* d_in, const int* in_sizes, int n_in,
                              void* d_out, int out_size, void* d_ws, size_t ws_size,
                              hipStream_t stream)
{
    const float* arr   = (const float*)d_in[0];
    const float* cbook = (const float*)d_in[1];
    float* out = (float*)d_out;
    // 4096 chains, 2 chains per single-wave 64-thread block -> 2048 blocks
    viterbi_q<<<dim3(2048), dim3(64), 0, stream>>>(arr, cbook, out);
}

// Round 5
// 110.096 us; speedup vs baseline: 1.0442x; 1.0442x over previous
//
#include <hip/hip_runtime.h>

// Viterbi trellis quantizer: S=1024 states, K=2 (4 predecessors), CHUNK=4,
// block_size=16 -> T=64 steps/chain, B=4096 chains (16x16 blocks of 1024^2).
//
// beta-formulation: beta_t[s] = M_{t-1}[s>>2] + (cb[s]·x_t + h[s]),
//   h = -||cb||^2/2, M_t[p] = max_j beta_t[p + 256j], M_{-1} = 0.
// Backpointer J[t][p] = argmax_j (first-max) -> traceback s_t = p + 256*J[t][p].
//
// R7. Model resolved by R3..R6 cross-checks: VALUBusy uses the gfx94x
// SIMD-16 formula (4cyc/instr) on SIMD-32 HW -> instr/chain-step ~126 =
// source count in EVERY round; we are LATENCY-bound at ~46% issue occupancy
// with only ~2.4 resident waves/SIMD (AGPR-banked 80-reg codebook caps
// residency; occupancy counter = 30%). Issue floor ~27us, measured 57.5.
//
// Fix residency: ONE chain per 256-thread block; thread tid owns group
// p = tid (4 states {tid+256j}), codebook 80 -> 20 regs/thread. Demand ~50
// fits 64 VGPRs -> 8 waves/SIMD; LDS ~19KB -> 8 blocks/CU (also 8 waves).
// Cross-wave M exchange: ping-pong M buffers + ONE __syncthreads per step
// (write buf^1 while reading buf -> no read/write race, single barrier).
// Decisions bit-identical to R3: same fmaf chain per state, same grouping,
// same first-max tie-breaks. Tripwire: WRITE_SIZE > 5120 KB = spill.

#define COLS      1024
#define T_STEPS   64
#define REC_SIZE  (1024 * 1024)

__global__ __launch_bounds__(256)
__attribute__((amdgpu_waves_per_eu(4, 8)))
void viterbi_q(
    const float* __restrict__ arr,
    const float* __restrict__ cbook,
    float* __restrict__ out)
{
    const int tid   = threadIdx.x;       // 0..255; owns trellis group p = tid
    const int lane  = tid & 63;
    const int wid   = tid >> 6;
    const int chain = blockIdx.x;        // one chain per block
    const int rb    = chain >> 6;
    const int cb    = chain & 63;

    __shared__ __align__(16) float tile[256];      // x chunks for the chain
    __shared__ __align__(16) float Mbuf[2][256];   // ping-pong grouped-max M
    __shared__ unsigned char J[63 * 256];          // backpointer per (t, p)
    __shared__ int   st_lds[64];                   // traced-back states
    __shared__ float redv[4];                      // cross-wave argmax scratch
    __shared__ int   reds[4];

    // ---- stage the 16x16 tile into LDS (tile[e], e = r*16 + c) ----
    if (tid < 64) {
        const int r  = tid >> 2;
        const int c4 = (tid & 3) << 2;
        float4 v = *(const float4*)(arr + (rb * 16 + r) * COLS + cb * 16 + c4);
        *(float4*)&tile[tid << 2] = v;
    }
    Mbuf[0][tid] = 0.f;   // M_{-1} = 0: step 0 computes beta0 = cb·x0 + h

    // ---- codebook rows for this thread's 4 states: s = tid + 256j ----
    float4 a[4];
    float  h[4];
    #pragma unroll
    for (int j = 0; j < 4; ++j) {
        float4 v = *(const float4*)(cbook + (tid + (j << 8)) * 4);
        a[j] = v;
        h[j] = -0.5f * (v.x * v.x + v.y * v.y + v.z * v.z + v.w * v.w);
    }

    __syncthreads();

    // one trellis step: read M from Mbuf[RB], write M_new to Mbuf[WB].
    // mj[j] = M[(tid>>2) + 64j]; candidates ascend in j (first-max = lowest
    // state, matching reference first-min over alpha).
#define STEP(T, RB, WB)                                                       \
    {                                                                         \
        const float4 xt = *(const float4*)&tile[(T) << 2];                    \
        float cand[4];                                                        \
        _Pragma("unroll")                                                     \
        for (int j = 0; j < 4; ++j) {                                         \
            const float m = Mbuf[RB][(tid >> 2) + (j << 6)];                  \
            float acc = fmaf(a[j].x, xt.x, h[j]);                             \
            acc = fmaf(a[j].y, xt.y, acc);                                    \
            acc = fmaf(a[j].z, xt.z, acc);                                    \
            acc = fmaf(a[j].w, xt.w, acc);                                    \
            cand[j] = acc + m;                                                \
        }                                                                     \
        const float v = fmaxf(fmaxf(fmaxf(cand[0], cand[1]), cand[2]),        \
                              cand[3]);                                       \
        const int jidx = (cand[0] == v) ? 0                                   \
                       : (cand[1] == v) ? 1                                   \
                       : (cand[2] == v) ? 2 : 3;                              \
        Mbuf[WB][tid] = v;                                                    \
        J[(T) * 256 + tid] = (unsigned char)jidx;                             \
    }

    // ---- forward recursion, t = 0..62 (31 pairs + 1), 1 barrier/step ----
    #pragma unroll 1
    for (int t = 0; t < 62; t += 2) {
        STEP(t, 0, 1);
        __syncthreads();
        STEP(t + 1, 1, 0);
        __syncthreads();
    }
    STEP(62, 0, 1);
    __syncthreads();
#undef STEP

    // ---- final step t = 63: beta_63 for this thread's 4 states, argmax ----
    {
        const float4 xt = *(const float4*)&tile[63 << 2];
        float bv = -3.4e38f;
        int   bs = 0;
        #pragma unroll
        for (int j = 0; j < 4; ++j) {    // states ascend in j: first-max ok
            const float m = Mbuf[1][(tid >> 2) + (j << 6)];
            float acc = fmaf(a[j].x, xt.x, h[j]);
            acc = fmaf(a[j].y, xt.y, acc);
            acc = fmaf(a[j].z, xt.z, acc);
            acc = fmaf(a[j].w, xt.w, acc);
            acc += m;
            if (acc > bv) { bv = acc; bs = tid + (j << 8); }
        }
        // lexicographic (value desc, state asc) butterfly within the wave
        #pragma unroll
        for (int off = 32; off > 0; off >>= 1) {
            const float ov = __shfl_xor(bv, off, 64);
            const int   os = __shfl_xor(bs, off, 64);
            if (ov > bv || (ov == bv && os < bs)) { bv = ov; bs = os; }
        }
        if (lane == 0) { redv[wid] = bv; reds[wid] = bs; }
    }
    __syncthreads();

    // ---- cross-wave combine + serial traceback (thread 0) ----
    if (tid == 0) {
        float gv = redv[0];
        int   gs = reds[0];
        #pragma unroll
        for (int w = 1; w < 4; ++w) {
            if (redv[w] > gv || (redv[w] == gv && reds[w] < gs)) {
                gv = redv[w];
                gs = reds[w];
            }
        }
        int s = gs;
        st_lds[T_STEPS - 1] = s;
        for (int i = T_STEPS - 2; i >= 0; --i) {
            const int p = s >> 2;
            const int j = J[i * 256 + p];
            s = p + (j << 8);
            st_lds[i] = s;
        }
    }
    __syncthreads();

    // ---- outputs: wave 0, lane t handles step t ----
    if (tid < 64) {
        const int st = st_lds[tid];
        // states_out flat: REC_SIZE + chain*64 + t   (stored as float values)
        out[REC_SIZE + chain * 64 + tid] = (float)st;
        // rec: step t covers elements e = 4t..4t+3 -> row t>>2, cols 4*(t&3)..
        const float4 v = *(const float4*)(cbook + st * 4);
        const int r  = tid >> 2;
        const int c4 = (tid & 3) << 2;
        *(float4*)(out + (rb * 16 + r) * COLS + cb * 16 + c4) = v;
    }
}

extern "C" void kernel_launch(void* const* d_in, const int* in_sizes, int n_in,
                              void* d_out, int out_size, void* d_ws, size_t ws_size,
                              hipStream_t stream)
{
    const float* arr   = (const float*)d_in[0];
    const float* cbook = (const float*)d_in[1];
    float* out = (float*)d_out;
    // 4096 chains, 1 chain per 256-thread block
    viterbi_q<<<dim3(4096), dim3(256), 0, stream>>>(arr, cbook, out);
}